// Round 7
// baseline (810.651 us; speedup 1.0000x reference)
//
#include <hip/hip_runtime.h>
#include <hip/hip_bf16.h>
#include <stdint.h>

// Problem constants (QRNN layer: SEQ=4096, BATCH=8, IN=1024, HID=1024)
#define S_   4096
#define B_   8
#define IN_  1024
#define H_   1024
#define M_   (S_ * B_)     // 32768 rows of the GEMM (row = s*B + b)
#define N_   (3 * H_)      // 3072 output cols (Z | F | O)
#define K_   IN_           // 1024
#define CH_  (B_ * H_)     // 8192 independent scan channels
#define NC_  64            // scan chunks
#define T_   (S_ / NC_)    // 64 steps per chunk

typedef unsigned short u16;
typedef __bf16 bf16x8 __attribute__((ext_vector_type(8)));
typedef float  f32x4  __attribute__((ext_vector_type(4)));
typedef _Float16 h8   __attribute__((ext_vector_type(8)));

__device__ __forceinline__ u16 f2bf(float f) {
  unsigned u = __float_as_uint(f);
  u += 0x7fffu + ((u >> 16) & 1u);   // round-to-nearest-even
  return (u16)(u >> 16);
}

__device__ __forceinline__ float sigmoid_(float x) { return 1.0f / (1.0f + __expf(-x)); }
__device__ __forceinline__ float tanh_(float x)    { return 2.0f / (1.0f + __expf(-2.0f * x)) - 1.0f; }

// ---- fused fp32 -> bf16 conversion for X and W; also resets scan flags -----
__global__ void cvt_all(const float* __restrict__ X, const float* __restrict__ W,
                        u16* __restrict__ Xb, u16* __restrict__ Wb,
                        unsigned* __restrict__ flags) {
  if (blockIdx.x == 0 && threadIdx.x < 256) flags[threadIdx.x] = 0;
  const int nX = M_ * K_ / 8, nW = N_ * K_ / 8;
  int i = blockIdx.x * blockDim.x + threadIdx.x;
  const float* in; u16* out; int j;
  if (i < nX)           { in = X; out = Xb; j = i; }
  else if (i < nX + nW) { in = W; out = Wb; j = i - nX; }
  else return;
  const float4* p = (const float4*)in;
  float4 a = p[2 * j], b = p[2 * j + 1];
  alignas(16) u16 us[8] = {f2bf(a.x), f2bf(a.y), f2bf(a.z), f2bf(a.w),
                           f2bf(b.x), f2bf(b.y), f2bf(b.z), f2bf(b.w)};
  ((uint4*)out)[j] = *(const uint4*)us;
}

// =============================================================================
// 256x256 8-phase bf16 MFMA GEMM (NT). Mainloop UNCHANGED (control).
// Epilogue: segs Z,F -> fp16 packed via LDS (XOR bank-swizzle) then 16B/lane
// full-line stores into interleaved G[m][2][1024]; seg O -> direct fp32 to Ho
// (full-line: 16 lanes x 4B = 64B).
// =============================================================================
#define SWZ(x) ((x) ^ (((x) >> 3) & 0x30))

#define DS_A(s, h, mh) do {                                                    \
  const char* base_ = (const char*)As_[(s)*2+(h)];                             \
  af[0] = *(const bf16x8*)(base_ + aoff[mh][0]);                               \
  af[1] = *(const bf16x8*)(base_ + aoff[mh][1]);                               \
  af[2] = *(const bf16x8*)(base_ + aoff[mh][2]);                               \
  af[3] = *(const bf16x8*)(base_ + aoff[mh][3]);                               \
} while (0)

#define DS_B(s, h) do {                                                        \
  const char* base_ = (const char*)Bs_[(s)*2+(h)];                             \
  bfr[0] = *(const bf16x8*)(base_ + boff[0]);                                  \
  bfr[1] = *(const bf16x8*)(base_ + boff[1]);                                  \
  bfr[2] = *(const bf16x8*)(base_ + boff[2]);                                  \
  bfr[3] = *(const bf16x8*)(base_ + boff[3]);                                  \
} while (0)

#define MMA(mh) do {                                                           \
  __builtin_amdgcn_s_setprio(1);                                              \
  _Pragma("unroll")                                                            \
  for (int fi_ = 0; fi_ < 4; ++fi_)                                            \
    _Pragma("unroll")                                                          \
    for (int fj_ = 0; fj_ < 4; ++fj_)                                          \
      acc[(mh)*4+fi_][fj_] = __builtin_amdgcn_mfma_f32_16x16x32_bf16(          \
          af[fi_], bfr[fj_], acc[(mh)*4+fi_][fj_], 0, 0, 0);                   \
  __builtin_amdgcn_s_setprio(0);                                              \
} while (0)

#define PH_SYNC() do {                                                         \
  asm volatile("" ::: "memory");                                               \
  __builtin_amdgcn_s_barrier();                                                \
  asm volatile("s_waitcnt lgkmcnt(0)" ::: "memory");                           \
} while (0)

#define PH_END() do {                                                          \
  asm volatile("" ::: "memory");                                               \
  __builtin_amdgcn_s_barrier();                                                \
} while (0)

#define VW(n) asm volatile("s_waitcnt vmcnt(" #n ")" ::: "memory")

__global__ __launch_bounds__(512, 2) void gemm_act(
    const u16* __restrict__ Ab, const u16* __restrict__ Bb,
    const float* __restrict__ bias,
    _Float16* __restrict__ G,   // [M_][2][1024] fp16: z (g=0), f (g=1)
    float* __restrict__ Ho) {   // sigm(O) fp32 -> H region of d_out
  __shared__ alignas(16) u16 As_[4][8192];
  __shared__ alignas(16) u16 Bs_[4][8192];

  const int tid = threadIdx.x;
  const int w = tid >> 6, l = tid & 63;
  const int m0 = blockIdx.y * 256, n0 = blockIdx.x * 256;
  const int wmo = (w >> 2) * 128, wno = (w & 3) * 64;
  const int lr = l & 15, lq = l >> 4;

  const int D0b  = w * 1024 + l * 16;
  const int row0 = D0b >> 6;
  const int c0   = (SWZ(D0b) & 63) >> 1;

  int aoff[2][4], boff[4];
#pragma unroll
  for (int mh = 0; mh < 2; ++mh)
#pragma unroll
    for (int fi = 0; fi < 4; ++fi)
      aoff[mh][fi] = SWZ((wmo + (mh * 4 + fi) * 16 + lr) * 64 + lq * 16);
#pragma unroll
  for (int fj = 0; fj < 4; ++fj)
    boff[fj] = SWZ((wno + fj * 16 + lr) * 64 + lq * 16);

  auto stage = [&](const u16* __restrict__ Gg, int rb, int tt, int hh, u16* dstp) {
    const u16* s0 = Gg + (size_t)(rb + row0) * K_ + (tt * 64 + hh * 32 + c0);
    __builtin_amdgcn_global_load_lds(
        (const __attribute__((address_space(1))) void*)s0,
        (__attribute__((address_space(3))) void*)(dstp + (D0b >> 1)), 16, 0, 0);
    const u16* s1 = s0 + (size_t)128 * K_;
    __builtin_amdgcn_global_load_lds(
        (const __attribute__((address_space(1))) void*)s1,
        (__attribute__((address_space(3))) void*)(dstp + (D0b >> 1) + 4096), 16, 0, 0);
  };

  f32x4 acc[8][4] = {};
  bf16x8 af[4], bfr[4];

  stage(Ab, m0, 0, 0, As_[0]); stage(Bb, n0, 0, 0, Bs_[0]);
  stage(Ab, m0, 0, 1, As_[1]); stage(Bb, n0, 0, 1, Bs_[1]);
  stage(Ab, m0, 1, 0, As_[2]); stage(Bb, n0, 1, 0, Bs_[2]);
  VW(4);
  PH_END();

  for (int i = 0; i < 7; ++i) {
    const int t1 = 2 * i + 1, t2 = 2 * i + 2, t3 = 2 * i + 3;
    DS_A(0, 0, 0); DS_B(0, 0); stage(Ab, m0, t1, 1, As_[3]);
    PH_SYNC(); MMA(0); PH_END();
    DS_A(0, 0, 1);             stage(Bb, n0, t1, 1, Bs_[3]);
    PH_SYNC(); MMA(1); PH_END();
    DS_A(0, 1, 0); DS_B(0, 1); stage(Ab, m0, t2, 0, As_[0]);
    PH_SYNC(); MMA(0); PH_END();
    DS_A(0, 1, 1);             stage(Bb, n0, t2, 0, Bs_[0]); VW(4);
    PH_SYNC(); MMA(1); PH_END();
    DS_A(1, 0, 0); DS_B(1, 0); stage(Ab, m0, t2, 1, As_[1]);
    PH_SYNC(); MMA(0); PH_END();
    DS_A(1, 0, 1);             stage(Bb, n0, t2, 1, Bs_[1]);
    PH_SYNC(); MMA(1); PH_END();
    DS_A(1, 1, 0); DS_B(1, 1); stage(Ab, m0, t3, 0, As_[2]);
    PH_SYNC(); MMA(0); PH_END();
    DS_A(1, 1, 1);             stage(Bb, n0, t3, 0, Bs_[2]); VW(4);
    PH_SYNC(); MMA(1); PH_END();
  }

  DS_A(0, 0, 0); DS_B(0, 0); stage(Ab, m0, 15, 1, As_[3]);
  PH_SYNC(); MMA(0); PH_END();
  DS_A(0, 0, 1);             stage(Bb, n0, 15, 1, Bs_[3]);
  PH_SYNC(); MMA(1); PH_END();
  DS_A(0, 1, 0); DS_B(0, 1);
  PH_SYNC(); MMA(0); PH_END();
  DS_A(0, 1, 1); VW(0);
  PH_SYNC(); MMA(1); PH_END();
  DS_A(1, 0, 0); DS_B(1, 0);
  PH_SYNC(); MMA(0); PH_END();
  DS_A(1, 0, 1);
  PH_SYNC(); MMA(1); PH_END();
  DS_A(1, 1, 0); DS_B(1, 1);
  PH_SYNC(); MMA(0); PH_END();
  DS_A(1, 1, 1);
  PH_SYNC(); MMA(1); PH_END();

  const int seg = n0 >> 10;
  if (seg == 2) {
    // direct fp32 stores (16 lanes x 4B = full 64B line) -- proven clean path
    const int nh0 = (n0 & 1023) + wno;
#pragma unroll
    for (int fj = 0; fj < 4; ++fj) {
      const int nn = nh0 + fj * 16 + lr;
      const float bv = bias[2048 + nn];
#pragma unroll
      for (int fi = 0; fi < 8; ++fi) {
#pragma unroll
        for (int rr = 0; rr < 4; ++rr) {
          const int mm = m0 + wmo + fi * 16 + lq * 4 + rr;
          Ho[(size_t)mm * H_ + nn] = sigmoid_(acc[fi][fj][rr] + bv);
        }
      }
    }
  } else {
    // pack fp16 tile into LDS (rows 0..127 -> As_, 128..255 -> Bs_), XOR
    // bank-swizzle at 16B granularity, then 16B/lane coalesced global stores.
    _Float16* myhalf = (_Float16*)((wmo == 0) ? (u16*)As_ : (u16*)Bs_);
#pragma unroll
    for (int fj = 0; fj < 4; ++fj) {
      const int col = wno + fj * 16 + lr;                  // 0..255 in tile
      const float bv = bias[seg * 1024 + (n0 & 1023) + col];
#pragma unroll
      for (int fi = 0; fi < 8; ++fi) {
#pragma unroll
        for (int rr = 0; rr < 4; ++rr) {
          const int row = wmo + fi * 16 + lq * 4 + rr;     // 0..255
          const float v = acc[fi][fj][rr] + bv;
          const float av = (seg == 0) ? tanh_(v) : sigmoid_(v);
          const int off = ((row & 127) << 9) + ((col * 2) ^ ((row & 15) << 4));
          *(_Float16*)((char*)myhalf + off) = (_Float16)av;
        }
      }
    }
    __syncthreads();
    // read-out: 512 threads x 16 iters; row=(tid>>5)+k*16, chunk=tid&31 (16B)
    const int chk = tid & 31;
#pragma unroll
    for (int k = 0; k < 16; ++k) {
      const int row = (tid >> 5) + k * 16;
      const char* half_ = (const char*)((row < 128) ? (u16*)As_ : (u16*)Bs_);
      const h8 v = *(const h8*)(half_ + ((row & 127) << 9) +
                                ((chk * 16) ^ ((row & 15) << 4)));
      const size_t dsth8 = (size_t)(m0 + row) * 256 + seg * 128 +
                           ((n0 & 1023) >> 3) + chk;
      ((h8*)G)[dsth8] = v;
    }
  }
}

// =============================================================================
// Fused scan, single kernel, NO cooperative launch. 256 blocks (grid 4x64) --
// guaranteed co-resident on 256 CUs -> flag polling is deadlock-free.
// pass A (read G) -> publish (release) -> poll predecessors (acquire) ->
// redundant combine (bit-identical to scanComb) -> pass B (G re-read is
// L3-resident: 128MB < 256MB) writing C + H, Clast.
// =============================================================================
__global__ __launch_bounds__(256) void fused_scan(
    const _Float16* __restrict__ G,   // [M_][2][1024] z,f
    float* __restrict__ Ho,           // in: sigm(O), out: H (in-place)
    float* __restrict__ Cw,           // C out fp32 [S,B,H]
    float* __restrict__ Clast,        // [CH_]
    const float* __restrict__ hidden,
    float* __restrict__ ckA, float* __restrict__ ckC,
    unsigned* __restrict__ flags) {
  const int x = blockIdx.x, j = blockIdx.y;
  const int tid = threadIdx.x;
  const int ch8 = x * 256 + tid;            // 0..1023 (8 channels each)
  const int b = ch8 >> 7, hh = ch8 & 127;
  const h8* __restrict__ G8 = (const h8*)G;
  const size_t STEP = 2048;                 // h8 (and float4) units per step

  // ---- pass A: (A = prod(1-f), c_local with c_in = 0), depth-2 prefetch
  float A[8], c[8];
#pragma unroll
  for (int k = 0; k < 8; ++k) { A[k] = 1.f; c[k] = 0.f; }
  size_t base = ((size_t)j * T_ * 8 + b) * 256 + hh;   // z at +0, f at +128
  h8 z0 = G8[base],        f0 = G8[base + 128];
  h8 z1 = G8[base + STEP], f1 = G8[base + STEP + 128];
  for (int tt = 0; tt < T_ - 2; ++tt) {
    const h8 z2 = G8[base + 2 * STEP];
    const h8 f2 = G8[base + 2 * STEP + 128];
#pragma unroll
    for (int k = 0; k < 8; ++k) {
      const float f = (float)f0[k], z = (float)z0[k], om = 1.f - f;
      c[k] = f * z + om * c[k]; A[k] *= om;
    }
    f0 = f1; z0 = z1; f1 = f2; z1 = z2; base += STEP;
  }
#pragma unroll
  for (int k = 0; k < 8; ++k) {
    const float f = (float)f0[k], z = (float)z0[k], om = 1.f - f;
    c[k] = f * z + om * c[k]; A[k] *= om;
  }
#pragma unroll
  for (int k = 0; k < 8; ++k) {
    const float f = (float)f1[k], z = (float)z1[k], om = 1.f - f;
    c[k] = f * z + om * c[k]; A[k] *= om;
  }
  {
    float4* a4 = (float4*)ckA; float4* c4 = (float4*)ckC;
    const size_t o4 = (size_t)j * STEP + ch8 * 2;
    a4[o4]     = float4{A[0], A[1], A[2], A[3]};
    a4[o4 + 1] = float4{A[4], A[5], A[6], A[7]};
    c4[o4]     = float4{c[0], c[1], c[2], c[3]};
    c4[o4 + 1] = float4{c[4], c[5], c[6], c[7]};
  }
  __syncthreads();
  __threadfence();
  if (tid == 0)
    __hip_atomic_store(&flags[x * 64 + j], 1u, __ATOMIC_RELEASE,
                       __HIP_MEMORY_SCOPE_AGENT);

  // ---- wait for predecessors (x, 0..j-1); thread i polls flag i
  if (tid < j) {
    while (__hip_atomic_load(&flags[x * 64 + tid], __ATOMIC_ACQUIRE,
                             __HIP_MEMORY_SCOPE_AGENT) == 0u)
      __builtin_amdgcn_s_sleep(2);
  }
  __syncthreads();

  // ---- redundant combine (identical op order to scanComb)
  float cin[8];
  {
    const float4 ha = ((const float4*)hidden)[ch8 * 2];
    const float4 hb = ((const float4*)hidden)[ch8 * 2 + 1];
    cin[0]=ha.x; cin[1]=ha.y; cin[2]=ha.z; cin[3]=ha.w;
    cin[4]=hb.x; cin[5]=hb.y; cin[6]=hb.z; cin[7]=hb.w;
  }
  {
    const float4* a4 = (const float4*)ckA;
    const float4* c4 = (const float4*)ckC;
    for (int i = 0; i < j; ++i) {
      const size_t o4 = (size_t)i * STEP + ch8 * 2;
      const float4 Aa = a4[o4], Ab = a4[o4 + 1];
      const float4 Ca = c4[o4], Cb = c4[o4 + 1];
      cin[0] = Ca.x + Aa.x * cin[0]; cin[1] = Ca.y + Aa.y * cin[1];
      cin[2] = Ca.z + Aa.z * cin[2]; cin[3] = Ca.w + Aa.w * cin[3];
      cin[4] = Cb.x + Ab.x * cin[4]; cin[5] = Cb.y + Ab.y * cin[5];
      cin[6] = Cb.z + Ab.z * cin[6]; cin[7] = Cb.w + Ab.w * cin[7];
    }
  }

  // ---- pass B: replay with true carry (G re-read L3-warm), write C, H
#pragma unroll
  for (int k = 0; k < 8; ++k) c[k] = cin[k];
  base = ((size_t)j * T_ * 8 + b) * 256 + hh;
  size_t b4 = ((size_t)j * T_ * 8 + b) * 256 + hh * 2;   // float4 units
  float4* __restrict__ H4 = (float4*)Ho;
  float4* __restrict__ C4 = (float4*)Cw;
  z0 = G8[base];        f0 = G8[base + 128];
  z1 = G8[base + STEP]; f1 = G8[base + STEP + 128];
  float4 oa0 = H4[b4], ob0 = H4[b4 + 1];
  float4 oa1 = H4[b4 + STEP], ob1 = H4[b4 + STEP + 1];
  for (int tt = 0; tt < T_ - 2; ++tt) {
    const h8 z2 = G8[base + 2 * STEP];
    const h8 f2 = G8[base + 2 * STEP + 128];
    const float4 oa2 = H4[b4 + 2 * STEP], ob2 = H4[b4 + 2 * STEP + 1];
#pragma unroll
    for (int k = 0; k < 8; ++k) {
      const float f = (float)f0[k], z = (float)z0[k];
      c[k] = f * z + (1.f - f) * c[k];
    }
    C4[b4]     = float4{c[0], c[1], c[2], c[3]};
    C4[b4 + 1] = float4{c[4], c[5], c[6], c[7]};
    H4[b4]     = float4{oa0.x * c[0], oa0.y * c[1], oa0.z * c[2], oa0.w * c[3]};
    H4[b4 + 1] = float4{ob0.x * c[4], ob0.y * c[5], ob0.z * c[6], ob0.w * c[7]};
    f0 = f1; z0 = z1; oa0 = oa1; ob0 = ob1;
    f1 = f2; z1 = z2; oa1 = oa2; ob1 = ob2;
    base += STEP; b4 += STEP;
  }
#pragma unroll
  for (int k = 0; k < 8; ++k) {
    const float f = (float)f0[k], z = (float)z0[k];
    c[k] = f * z + (1.f - f) * c[k];
  }
  C4[b4]     = float4{c[0], c[1], c[2], c[3]};
  C4[b4 + 1] = float4{c[4], c[5], c[6], c[7]};
  H4[b4]     = float4{oa0.x * c[0], oa0.y * c[1], oa0.z * c[2], oa0.w * c[3]};
  H4[b4 + 1] = float4{ob0.x * c[4], ob0.y * c[5], ob0.z * c[6], ob0.w * c[7]};
  b4 += STEP;
#pragma unroll
  for (int k = 0; k < 8; ++k) {
    const float f = (float)f1[k], z = (float)z1[k];
    c[k] = f * z + (1.f - f) * c[k];
  }
  C4[b4]     = float4{c[0], c[1], c[2], c[3]};
  C4[b4 + 1] = float4{c[4], c[5], c[6], c[7]};
  H4[b4]     = float4{oa1.x * c[0], oa1.y * c[1], oa1.z * c[2], oa1.w * c[3]};
  H4[b4 + 1] = float4{ob1.x * c[4], ob1.y * c[5], ob1.z * c[6], ob1.w * c[7]};
  if (j == NC_ - 1) {
    ((float4*)Clast)[ch8 * 2]     = float4{c[0], c[1], c[2], c[3]};
    ((float4*)Clast)[ch8 * 2 + 1] = float4{c[4], c[5], c[6], c[7]};
  }
}

extern "C" void kernel_launch(void* const* d_in, const int* in_sizes, int n_in,
                              void* d_out, int out_size, void* d_ws, size_t ws_size,
                              hipStream_t stream) {
  const float* X    = (const float*)d_in[0];   // [S,B,IN]
  const float* hid  = (const float*)d_in[1];   // [B,H]
  const float* W    = (const float*)d_in[2];   // [3H,IN]
  const float* bias = (const float*)d_in[3];   // [3H]

  float* out   = (float*)d_out;
  float* Ho    = out;                          // H       [S,B,H]
  float* Clast = out + (size_t)M_ * H_;        // C[-1:]  [1,B,H]
  float* Cf    = Clast + CH_;                  // C       [S,B,H]

  char* ws = (char*)d_ws;
  u16*      Xb   = (u16*)ws;                   //  67108864 B bf16 X
  u16*      Wb   = (u16*)(ws + 67108864);      //   6291456 B bf16 W
  _Float16* Gh   = (_Float16*)(ws + 73400320); // 134217728 B fp16 [M][2][1024]
  float*    ckA  = (float*)(ws + 207618048);   //   2097152 B
  float*    ckC  = (float*)(ws + 209715200);   //   2097152 B
  unsigned* flags= (unsigned*)(ws + 211812352);//      1024 B  (total ~202 MiB)

  const int nAll = M_ * K_ / 8 + N_ * K_ / 8;
  cvt_all<<<(nAll + 255) / 256, 256, 0, stream>>>(X, W, Xb, Wb, flags);
  gemm_act<<<dim3(N_ / 256, M_ / 256), 512, 0, stream>>>(Xb, Wb, bias, Gh, Ho);
  fused_scan<<<dim3(4, NC_), 256, 0, stream>>>(Gh, Ho, Cf, Clast, hid,
                                               ckA, ckC, flags);
}